// Round 1
// baseline (276.695 us; speedup 1.0000x reference)
//
#include <hip/hip_runtime.h>
#include <hip/hip_bf16.h>
#include <cstdint>
#include <cstddef>

typedef unsigned short u16;
typedef __bf16 bf16x8 __attribute__((ext_vector_type(8)));
typedef u16 ushort8 __attribute__((ext_vector_type(8)));
typedef float f32x4 __attribute__((ext_vector_type(4)));

#define EMB_DIM 128
#define KDIM 256
#define HID 256
#define MTILE 64

static __device__ __forceinline__ u16 f2bf(float f) {
    // RNE f32 -> bf16 (inputs are finite; no NaN path needed)
    uint32_t u = __builtin_bit_cast(uint32_t, f);
    u += 0x7fffu + ((u >> 16) & 1u);
    return (u16)(u >> 16);
}

// Pack W1 [K=256][N=256] f32 into MFMA-B fragment order, bf16:
// w1p[((ntg*8 + kki)*64 + lane)*8 + j] =
//   bf16( W1[(kki*32 + (lane>>4)*8 + j)*HID + ntg*16 + (lane&15)] )
// so each wave's B-fragment load is 64 consecutive 16B chunks (1 KiB, coalesced).
__global__ void prep_w1(const float* __restrict__ W1, u16* __restrict__ w1p) {
    int id = blockIdx.x * blockDim.x + threadIdx.x;   // 65536 total
    int j   = id & 7;
    int l   = (id >> 3) & 63;
    int kki = (id >> 9) & 7;
    int ntg = id >> 12;
    int k = kki * 32 + ((l >> 4) * 8) + j;
    int n = ntg * 16 + (l & 15);
    w1p[id] = f2bf(W1[k * HID + n]);
}

__launch_bounds__(256, 2)
__global__ void edge_mlp(const float* __restrict__ embs,
                         const int* __restrict__ nidx,
                         const u16* __restrict__ w1p,
                         const float* __restrict__ b1,
                         const float* __restrict__ W2,
                         const float* __restrict__ b2,
                         float* __restrict__ out,
                         int npairs) {
    // X tile: 64 rows x 256 cols bf16 = 32 KiB (XOR-swizzled) + 2 KiB partials
    __shared__ __align__(16) unsigned char lds[MTILE * 512 + 4 * MTILE * 2 * 4];
    const int t  = threadIdx.x;
    const int e0 = blockIdx.x * MTILE;

    // ---- stage gathered X tile into LDS as bf16, swizzled ----
    {
        const int row = t >> 2;   // pair row within tile, 0..63
        const int seg = t & 3;    // 64-float segment, 0..3
        const int e = e0 + row;
        if (e < npairs) {
            const int i0 = nidx[2 * e];
            const int i1 = nidx[2 * e + 1];
            const float* src = (seg < 2) ? (embs + (size_t)i0 * EMB_DIM)
                                         : (embs + (size_t)i1 * EMB_DIM);
            const int cbase = (seg & 1) * 64;   // col within that node's 128
            #pragma unroll
            for (int j = 0; j < 8; ++j) {
                const int c = cbase + j * 8;
                float4 f0 = *reinterpret_cast<const float4*>(src + c);
                float4 f1 = *reinterpret_cast<const float4*>(src + c + 4);
                ushort8 h;
                h[0] = f2bf(f0.x); h[1] = f2bf(f0.y);
                h[2] = f2bf(f0.z); h[3] = f2bf(f0.w);
                h[4] = f2bf(f1.x); h[5] = f2bf(f1.y);
                h[6] = f2bf(f1.z); h[7] = f2bf(f1.w);
                int off = row * 512 + (seg * 64 + j * 8) * 2;  // byte offset
                off ^= (row & 7) << 4;                          // st-swizzle
                *reinterpret_cast<ushort8*>(lds + off) = h;
            }
        }
    }
    __syncthreads();

    const int w  = t >> 6;   // wave 0..3 -> owns cols [w*64, w*64+64)
    const int l  = t & 63;
    const int lg = l >> 4;   // k-chunk group
    const int lc = l & 15;

    f32x4 acc[4][4] = {};    // [m-tile][n-tile]

    #pragma unroll
    for (int kki = 0; kki < 8; ++kki) {          // K = 256 in steps of 32
        const int krow = kki * 32 + lg * 8;
        bf16x8 a[4], b[4];
        #pragma unroll
        for (int mt = 0; mt < 4; ++mt) {
            const int row = mt * 16 + lc;
            int off = row * 512 + krow * 2;
            off ^= (row & 7) << 4;
            a[mt] = *reinterpret_cast<const bf16x8*>(lds + off);
        }
        #pragma unroll
        for (int nt = 0; nt < 4; ++nt)
            b[nt] = *reinterpret_cast<const bf16x8*>(
                w1p + (size_t)(((w * 4 + nt) * 8 + kki) * 64 + l) * 8);
        #pragma unroll
        for (int mt = 0; mt < 4; ++mt)
            #pragma unroll
            for (int nt = 0; nt < 4; ++nt)
                acc[mt][nt] = __builtin_amdgcn_mfma_f32_16x16x32_bf16(
                    a[mt], b[nt], acc[mt][nt], 0, 0, 0);
    }

    // ---- fused epilogue: logits = relu(H + b1) @ W2 + b2 ----
    // C/D layout: col = lane&15, row = (lane>>4)*4 + reg   [m89-verified]
    float p0[4][4] = {}, p1[4][4] = {};
    #pragma unroll
    for (int nt = 0; nt < 4; ++nt) {
        const int n = w * 64 + nt * 16 + lc;
        const float bn  = b1[n];
        const float w20 = W2[2 * n];
        const float w21 = W2[2 * n + 1];
        #pragma unroll
        for (int mt = 0; mt < 4; ++mt)
            #pragma unroll
            for (int r = 0; r < 4; ++r) {
                float v = fmaxf(acc[mt][nt][r] + bn, 0.0f);
                p0[mt][r] = fmaf(v, w20, p0[mt][r]);
                p1[mt][r] = fmaf(v, w21, p1[mt][r]);
            }
    }
    // reduce over the 16 column-lanes of each group
    #pragma unroll
    for (int mt = 0; mt < 4; ++mt)
        #pragma unroll
        for (int r = 0; r < 4; ++r) {
            float a0 = p0[mt][r], a1 = p1[mt][r];
            #pragma unroll
            for (int mask = 1; mask < 16; mask <<= 1) {
                a0 += __shfl_xor(a0, mask);
                a1 += __shfl_xor(a1, mask);
            }
            p0[mt][r] = a0; p1[mt][r] = a1;
        }

    float* part = reinterpret_cast<float*>(lds + MTILE * 512);
    if (lc == 0) {
        #pragma unroll
        for (int mt = 0; mt < 4; ++mt)
            #pragma unroll
            for (int r = 0; r < 4; ++r) {
                const int m = mt * 16 + lg * 4 + r;
                part[(w * MTILE + m) * 2 + 0] = p0[mt][r];
                part[(w * MTILE + m) * 2 + 1] = p1[mt][r];
            }
    }
    __syncthreads();
    if (t < 2 * MTILE) {
        const int m = t >> 1, c = t & 1;
        if (e0 + m < npairs) {
            float s = b2[c];
            #pragma unroll
            for (int ww = 0; ww < 4; ++ww)
                s += part[(ww * MTILE + m) * 2 + c];
            out[(size_t)(e0 + m) * 2 + c] = s;
        }
    }
}

extern "C" void kernel_launch(void* const* d_in, const int* in_sizes, int n_in,
                              void* d_out, int out_size, void* d_ws, size_t ws_size,
                              hipStream_t stream) {
    const float* embs = (const float*)d_in[0];
    const int*   nidx = (const int*)d_in[1];
    const float* W1   = (const float*)d_in[2];
    const float* b1   = (const float*)d_in[3];
    const float* W2   = (const float*)d_in[4];
    const float* b2   = (const float*)d_in[5];
    float* out = (float*)d_out;
    u16*   w1p = (u16*)d_ws;     // 65536 * 2B = 128 KiB of workspace

    prep_w1<<<(KDIM * HID) / 256, 256, 0, stream>>>(W1, w1p);

    const int npairs = in_sizes[1] / 2;
    const int nblk = (npairs + MTILE - 1) / MTILE;
    edge_mlp<<<nblk, 256, 0, stream>>>(embs, nidx, w1p, b1, W2, b2, out, npairs);
}

// Round 2
// 197.314 us; speedup vs baseline: 1.4023x; 1.4023x over previous
//
#include <hip/hip_runtime.h>
#include <hip/hip_bf16.h>
#include <cstdint>
#include <cstddef>

typedef unsigned short u16;
typedef __bf16 bf16x8 __attribute__((ext_vector_type(8)));
typedef u16 ushort8 __attribute__((ext_vector_type(8)));
typedef float f32x4 __attribute__((ext_vector_type(4)));

#define EMB_DIM 128
#define KDIM 256
#define HID 256
#define MTILE 64

static __device__ __forceinline__ u16 f2bf(float f) {
    // RNE f32 -> bf16
    uint32_t u = __builtin_bit_cast(uint32_t, f);
    u += 0x7fffu + ((u >> 16) & 1u);
    return (u16)(u >> 16);
}

// Pack W1 [K=256][N=256] f32 into MFMA-B fragment order, bf16 (validated R1).
__global__ void prep_w1(const float* __restrict__ W1, u16* __restrict__ w1p) {
    int id = blockIdx.x * blockDim.x + threadIdx.x;   // 65536 total
    int j   = id & 7;
    int l   = (id >> 3) & 63;
    int kki = (id >> 9) & 7;
    int ntg = id >> 12;
    int k = kki * 32 + ((l >> 4) * 8) + j;
    int n = ntg * 16 + (l & 15);
    w1p[id] = f2bf(W1[k * HID + n]);
}

// Convert the whole embedding table f32 -> bf16 (row-major, same layout).
__global__ void prep_embs(const float* __restrict__ in, u16* __restrict__ out, int n) {
    int id = blockIdx.x * blockDim.x + threadIdx.x;
    size_t base = (size_t)id * 8;
    if (base + 8 <= (size_t)n) {
        float4 f0 = *reinterpret_cast<const float4*>(in + base);
        float4 f1 = *reinterpret_cast<const float4*>(in + base + 4);
        ushort8 h;
        h[0] = f2bf(f0.x); h[1] = f2bf(f0.y); h[2] = f2bf(f0.z); h[3] = f2bf(f0.w);
        h[4] = f2bf(f1.x); h[5] = f2bf(f1.y); h[6] = f2bf(f1.z); h[7] = f2bf(f1.w);
        *reinterpret_cast<ushort8*>(out + base) = h;
    }
}

static __device__ __forceinline__ void gload_lds16(const void* g, void* s) {
    __builtin_amdgcn_global_load_lds(
        (const __attribute__((address_space(1))) unsigned int*)g,
        (__attribute__((address_space(3))) unsigned int*)s, 16, 0, 0);
}

// Main kernel: bf16 table gather via global_load_lds (source-swizzled), MFMA GEMM,
// fused relu+W2 epilogue.
__launch_bounds__(256, 4)
__global__ void edge_mlp_bf(const u16* __restrict__ embT,
                            const int* __restrict__ nidx,
                            const u16* __restrict__ w1p,
                            const float* __restrict__ b1,
                            const float* __restrict__ W2,
                            const float* __restrict__ b2,
                            float* __restrict__ out,
                            int npairs) {
    // X tile: 64 rows x 256 cols bf16 = 32 KiB (LINEAR dest, source-swizzled)
    // + 2 KiB cross-wave partials
    __shared__ __align__(16) unsigned char lds[MTILE * 512 + 4 * MTILE * 2 * 4];
    const int t  = threadIdx.x;
    const int e0 = blockIdx.x * MTILE;
    const int w  = t >> 6;   // wave 0..3
    const int l  = t & 63;

    // ---- stage: wave w DMAs rows [w*16, w*16+16) ; 8 issues x 2 rows ----
    {
        // lanes 0..31 hold nidx[2*(e0+w*16) + l]  (node indices for 16 rows)
        int gmax = 2 * npairs - 1;
        int gi = 2 * (e0 + w * 16) + l;
        int vidx = nidx[gi < gmax ? gi : gmax];

        const int row_off = l >> 5;        // which of the 2 rows this lane fills
        const int csel    = (l >> 4) & 1;  // node0 vs node1 within a row
        const int c       = l & 31;        // 16B chunk within the 1KB (2-row) dest
        #pragma unroll
        for (int i = 0; i < 8; ++i) {
            int n00 = __builtin_amdgcn_readlane(vidx, 4 * i + 0);
            int n01 = __builtin_amdgcn_readlane(vidx, 4 * i + 1);
            int n10 = __builtin_amdgcn_readlane(vidx, 4 * i + 2);
            int n11 = __builtin_amdgcn_readlane(vidx, 4 * i + 3);
            int na   = csel ? n01 : n00;
            int nb   = csel ? n11 : n10;
            int node = row_off ? nb : na;
            int r    = w * 16 + 2 * i + row_off;
            // source-swizzle: LDS chunk c of row r receives global chunk c^(r&7)
            int glow = (c ^ (r & 7)) & 15;           // 16B chunk within node's 256B
            const u16* src = embT + (size_t)node * 128 + glow * 8;
            gload_lds16(src, lds + (w * 16 + 2 * i) * 512);  // uniform base; +lane*16 in HW
        }
    }
    __syncthreads();   // compiler drains vmcnt(0) before s_barrier

    const int lg = l >> 4;   // k-chunk group
    const int lc = l & 15;

    f32x4 acc[4][4] = {};    // [m-tile][n-tile]

    #pragma unroll
    for (int kki = 0; kki < 8; ++kki) {          // K = 256 in steps of 32
        bf16x8 a[4], b[4];
        const int ch = kki * 4 + lg;             // 16B chunk index along K
        #pragma unroll
        for (int mt = 0; mt < 4; ++mt) {
            const int row = mt * 16 + lc;
            const int off = row * 512 + ((ch ^ (row & 7)) << 4);
            a[mt] = *reinterpret_cast<const bf16x8*>(lds + off);
        }
        #pragma unroll
        for (int nt = 0; nt < 4; ++nt)
            b[nt] = *reinterpret_cast<const bf16x8*>(
                w1p + (size_t)(((w * 4 + nt) * 8 + kki) * 64 + l) * 8);
        #pragma unroll
        for (int mt = 0; mt < 4; ++mt)
            #pragma unroll
            for (int nt = 0; nt < 4; ++nt)
                acc[mt][nt] = __builtin_amdgcn_mfma_f32_16x16x32_bf16(
                    a[mt], b[nt], acc[mt][nt], 0, 0, 0);
    }

    // ---- fused epilogue: logits = relu(H + b1) @ W2 + b2 ----
    // C/D layout: col = lane&15, row = (lane>>4)*4 + reg   [m89-verified]
    float bn[4], w20[4], w21[4];
    #pragma unroll
    for (int nt = 0; nt < 4; ++nt) {
        const int n = w * 64 + nt * 16 + lc;
        bn[nt]  = b1[n];
        w20[nt] = W2[2 * n];
        w21[nt] = W2[2 * n + 1];
    }
    float* part = reinterpret_cast<float*>(lds + MTILE * 512);
    #pragma unroll
    for (int mt = 0; mt < 4; ++mt) {
        float p0[4] = {}, p1[4] = {};
        #pragma unroll
        for (int nt = 0; nt < 4; ++nt)
            #pragma unroll
            for (int r = 0; r < 4; ++r) {
                float v = fmaxf(acc[mt][nt][r] + bn[nt], 0.0f);
                p0[r] = fmaf(v, w20[nt], p0[r]);
                p1[r] = fmaf(v, w21[nt], p1[r]);
            }
        #pragma unroll
        for (int r = 0; r < 4; ++r) {
            float a0 = p0[r], a1 = p1[r];
            #pragma unroll
            for (int mask = 1; mask < 16; mask <<= 1) {
                a0 += __shfl_xor(a0, mask);
                a1 += __shfl_xor(a1, mask);
            }
            if (lc == 0) {
                const int m = mt * 16 + lg * 4 + r;
                part[(w * MTILE + m) * 2 + 0] = a0;
                part[(w * MTILE + m) * 2 + 1] = a1;
            }
        }
    }
    __syncthreads();
    if (t < 2 * MTILE) {
        const int m = t >> 1, c = t & 1;
        if (e0 + m < npairs) {
            float s = b2[c];
            #pragma unroll
            for (int ww = 0; ww < 4; ++ww)
                s += part[(ww * MTILE + m) * 2 + c];
            out[(size_t)(e0 + m) * 2 + c] = s;
        }
    }
}

// ---- Fallback (validated R1): f32 gather + in-kernel convert ----
__launch_bounds__(256, 2)
__global__ void edge_mlp_f32g(const float* __restrict__ embs,
                              const int* __restrict__ nidx,
                              const u16* __restrict__ w1p,
                              const float* __restrict__ b1,
                              const float* __restrict__ W2,
                              const float* __restrict__ b2,
                              float* __restrict__ out,
                              int npairs) {
    __shared__ __align__(16) unsigned char lds[MTILE * 512 + 4 * MTILE * 2 * 4];
    const int t  = threadIdx.x;
    const int e0 = blockIdx.x * MTILE;
    {
        const int row = t >> 2;
        const int seg = t & 3;
        const int e = e0 + row;
        if (e < npairs) {
            const int i0 = nidx[2 * e];
            const int i1 = nidx[2 * e + 1];
            const float* src = (seg < 2) ? (embs + (size_t)i0 * EMB_DIM)
                                         : (embs + (size_t)i1 * EMB_DIM);
            const int cbase = (seg & 1) * 64;
            #pragma unroll
            for (int j = 0; j < 8; ++j) {
                const int c = cbase + j * 8;
                float4 f0 = *reinterpret_cast<const float4*>(src + c);
                float4 f1 = *reinterpret_cast<const float4*>(src + c + 4);
                ushort8 h;
                h[0] = f2bf(f0.x); h[1] = f2bf(f0.y);
                h[2] = f2bf(f0.z); h[3] = f2bf(f0.w);
                h[4] = f2bf(f1.x); h[5] = f2bf(f1.y);
                h[6] = f2bf(f1.z); h[7] = f2bf(f1.w);
                int off = row * 512 + (seg * 64 + j * 8) * 2;
                off ^= (row & 7) << 4;
                *reinterpret_cast<ushort8*>(lds + off) = h;
            }
        }
    }
    __syncthreads();
    const int w  = t >> 6;
    const int l  = t & 63;
    const int lg = l >> 4;
    const int lc = l & 15;
    f32x4 acc[4][4] = {};
    #pragma unroll
    for (int kki = 0; kki < 8; ++kki) {
        const int krow = kki * 32 + lg * 8;
        bf16x8 a[4], b[4];
        #pragma unroll
        for (int mt = 0; mt < 4; ++mt) {
            const int row = mt * 16 + lc;
            int off = row * 512 + krow * 2;
            off ^= (row & 7) << 4;
            a[mt] = *reinterpret_cast<const bf16x8*>(lds + off);
        }
        #pragma unroll
        for (int nt = 0; nt < 4; ++nt)
            b[nt] = *reinterpret_cast<const bf16x8*>(
                w1p + (size_t)(((w * 4 + nt) * 8 + kki) * 64 + l) * 8);
        #pragma unroll
        for (int mt = 0; mt < 4; ++mt)
            #pragma unroll
            for (int nt = 0; nt < 4; ++nt)
                acc[mt][nt] = __builtin_amdgcn_mfma_f32_16x16x32_bf16(
                    a[mt], b[nt], acc[mt][nt], 0, 0, 0);
    }
    float p0[4][4] = {}, p1[4][4] = {};
    #pragma unroll
    for (int nt = 0; nt < 4; ++nt) {
        const int n = w * 64 + nt * 16 + lc;
        const float bnv  = b1[n];
        const float w20 = W2[2 * n];
        const float w21 = W2[2 * n + 1];
        #pragma unroll
        for (int mt = 0; mt < 4; ++mt)
            #pragma unroll
            for (int r = 0; r < 4; ++r) {
                float v = fmaxf(acc[mt][nt][r] + bnv, 0.0f);
                p0[mt][r] = fmaf(v, w20, p0[mt][r]);
                p1[mt][r] = fmaf(v, w21, p1[mt][r]);
            }
    }
    #pragma unroll
    for (int mt = 0; mt < 4; ++mt)
        #pragma unroll
        for (int r = 0; r < 4; ++r) {
            float a0 = p0[mt][r], a1 = p1[mt][r];
            #pragma unroll
            for (int mask = 1; mask < 16; mask <<= 1) {
                a0 += __shfl_xor(a0, mask);
                a1 += __shfl_xor(a1, mask);
            }
            p0[mt][r] = a0; p1[mt][r] = a1;
        }
    float* part = reinterpret_cast<float*>(lds + MTILE * 512);
    if (lc == 0) {
        #pragma unroll
        for (int mt = 0; mt < 4; ++mt)
            #pragma unroll
            for (int r = 0; r < 4; ++r) {
                const int m = mt * 16 + lg * 4 + r;
                part[(w * MTILE + m) * 2 + 0] = p0[mt][r];
                part[(w * MTILE + m) * 2 + 1] = p1[mt][r];
            }
    }
    __syncthreads();
    if (t < 2 * MTILE) {
        const int m = t >> 1, c = t & 1;
        if (e0 + m < npairs) {
            float s = b2[c];
            #pragma unroll
            for (int ww = 0; ww < 4; ++ww)
                s += part[(ww * MTILE + m) * 2 + c];
            out[(size_t)(e0 + m) * 2 + c] = s;
        }
    }
}

extern "C" void kernel_launch(void* const* d_in, const int* in_sizes, int n_in,
                              void* d_out, int out_size, void* d_ws, size_t ws_size,
                              hipStream_t stream) {
    const float* embs = (const float*)d_in[0];
    const int*   nidx = (const int*)d_in[1];
    const float* W1   = (const float*)d_in[2];
    const float* b1   = (const float*)d_in[3];
    const float* W2   = (const float*)d_in[4];
    const float* b2   = (const float*)d_in[5];
    float* out = (float*)d_out;

    u16* w1p = (u16*)d_ws;                       // 128 KiB
    prep_w1<<<(KDIM * HID) / 256, 256, 0, stream>>>(W1, w1p);

    const int npairs = in_sizes[1] / 2;
    const int nblk = (npairs + MTILE - 1) / MTILE;

    const size_t embT_off = 131072;              // after w1p, 2^17-aligned
    const size_t need = embT_off + (size_t)in_sizes[0] * sizeof(u16);
    if (ws_size >= need) {
        u16* embT = (u16*)((char*)d_ws + embT_off);
        const int nemb = in_sizes[0];
        prep_embs<<<(nemb + 2047) / 2048, 256, 0, stream>>>(embs, embT, nemb);
        edge_mlp_bf<<<nblk, 256, 0, stream>>>(embT, nidx, w1p, b1, W2, b2, out, npairs);
    } else {
        edge_mlp_f32g<<<nblk, 256, 0, stream>>>(embs, nidx, w1p, b1, W2, b2, out, npairs);
    }
}

// Round 3
// 152.685 us; speedup vs baseline: 1.8122x; 1.2923x over previous
//
#include <hip/hip_runtime.h>
#include <hip/hip_bf16.h>
#include <cstdint>
#include <cstddef>

typedef unsigned short u16;
typedef __bf16 bf16x8 __attribute__((ext_vector_type(8)));
typedef u16 ushort8 __attribute__((ext_vector_type(8)));
typedef float f32x4 __attribute__((ext_vector_type(4)));

#define EMB_DIM 128
#define KDIM 256
#define HID 256
#define MTILE 64
#define NBLK 512   // 2 blocks/CU * 256 CU (LDS-limited)

static __device__ __forceinline__ u16 f2bf(float f) {
    uint32_t u = __builtin_bit_cast(uint32_t, f);
    u += 0x7fffu + ((u >> 16) & 1u);
    return (u16)(u >> 16);
}

// W1 [K=256][N=256] f32 -> MFMA fragment order, bf16 (validated R1/R2).
// Serves as A-operand (m=hidden) in the swapped GEMM: layout identical.
__global__ void prep_w1(const float* __restrict__ W1, u16* __restrict__ w1p) {
    int id = blockIdx.x * blockDim.x + threadIdx.x;   // 65536
    int j   = id & 7;
    int l   = (id >> 3) & 63;
    int kki = (id >> 9) & 7;
    int ntg = id >> 12;
    int k = kki * 32 + ((l >> 4) * 8) + j;
    int n = ntg * 16 + (l & 15);
    w1p[id] = f2bf(W1[k * HID + n]);
}

// W2 [256][2] -> A-fragment (m=logit col, 2 of 16 used) with PERMUTED k-map
// k_local = g*4 + (j>>2)*16 + (j&3) so the B-operand is the raw cvt_pk'd
// accumulator words (no cross-lane moves). 8 chunks x 512 = 4096 elems.
__global__ void prep_w2(const float* __restrict__ W2, u16* __restrict__ w2ap) {
    int id = blockIdx.x * blockDim.x + threadIdx.x;   // 4096
    if (id >= 4096) return;
    int j   = id & 7;
    int l   = (id >> 3) & 63;
    int kki = id >> 9;
    int m = l & 15;
    int g = (l >> 4) & 3;
    int k = kki * 32 + g * 4 + ((j >> 2) << 4) + (j & 3);
    w2ap[id] = (m < 2) ? f2bf(W2[k * 2 + m]) : (u16)0;
}

// Embedding table f32 -> bf16 (row-major).
__global__ void prep_embs(const float* __restrict__ in, u16* __restrict__ out, int n) {
    int id = blockIdx.x * blockDim.x + threadIdx.x;
    size_t base = (size_t)id * 8;
    if (base + 8 <= (size_t)n) {
        float4 f0 = *reinterpret_cast<const float4*>(in + base);
        float4 f1 = *reinterpret_cast<const float4*>(in + base + 4);
        ushort8 h;
        h[0] = f2bf(f0.x); h[1] = f2bf(f0.y); h[2] = f2bf(f0.z); h[3] = f2bf(f0.w);
        h[4] = f2bf(f1.x); h[5] = f2bf(f1.y); h[6] = f2bf(f1.z); h[7] = f2bf(f1.w);
        *reinterpret_cast<ushort8*>(out + base) = h;
    }
}

static __device__ __forceinline__ void gload_lds16(const void* g, void* s) {
    __builtin_amdgcn_global_load_lds(
        (const __attribute__((address_space(1))) unsigned int*)g,
        (__attribute__((address_space(3))) unsigned int*)s, 16, 0, 0);
}

// Stage 16 edge rows (wave w) of gathered bf16 X into LDS, source-swizzled
// (validated R2 structure).
static __device__ __forceinline__ void stage_tile(const u16* __restrict__ embT,
                                                  int vidx, unsigned char* xb,
                                                  int w, int l) {
    const int row_off = l >> 5;
    const int csel    = (l >> 4) & 1;
    const int c       = l & 31;
    #pragma unroll
    for (int i = 0; i < 8; ++i) {
        int n00 = __builtin_amdgcn_readlane(vidx, 4 * i + 0);
        int n01 = __builtin_amdgcn_readlane(vidx, 4 * i + 1);
        int n10 = __builtin_amdgcn_readlane(vidx, 4 * i + 2);
        int n11 = __builtin_amdgcn_readlane(vidx, 4 * i + 3);
        int na   = csel ? n01 : n00;
        int nb   = csel ? n11 : n10;
        int node = row_off ? nb : na;
        int r2   = 2 * i + row_off;                 // row&7 (w*16 == 0 mod 8)
        int glow = (c ^ (r2 & 7)) & 15;
        const u16* src = embT + (size_t)node * 128 + glow * 8;
        gload_lds16(src, xb + (size_t)(w * 16 + 2 * i) * 512);
    }
}

__launch_bounds__(256, 2)
__global__ void edge_mlp_bf2(const u16* __restrict__ embT,
                             const int* __restrict__ nidx,
                             const u16* __restrict__ w1p,
                             const u16* __restrict__ w2ap,
                             const float* __restrict__ b1,
                             const float* __restrict__ b2,
                             float* __restrict__ out,
                             int npairs, int ntiles, int nb) {
    // 2 x 32 KiB X double-buffer + 2 KiB partials
    __shared__ __align__(16) unsigned char lds[2 * MTILE * 512 + 4 * MTILE * 2 * 4];
    const int t  = threadIdx.x;
    const int w  = t >> 6;
    const int l  = t & 63;
    const int lg = l >> 4;
    const int lc = l & 15;
    const int gmax = 2 * npairs - 1;

    // Hoisted constants
    float4 b1v[4];
    #pragma unroll
    for (int ht = 0; ht < 4; ++ht)
        b1v[ht] = *reinterpret_cast<const float4*>(b1 + w * 64 + ht * 16 + lg * 4);
    bf16x8 af2[2];
    #pragma unroll
    for (int kk = 0; kk < 2; ++kk)
        af2[kk] = *reinterpret_cast<const bf16x8*>(w2ap + (size_t)((w * 2 + kk) * 64 + l) * 8);
    const float b2c = b2[t & 1];   // used only by t<128 in tail

    // per-lane LDS read base: addr(kki,et) = (base0 ^ (kki<<6)) + et*8192 (+buf)
    const int base0 = lc * 512 + ((lg ^ (lc & 3)) << 4) + (((lc >> 2) & 1) << 6);

    float2* part = reinterpret_cast<float2*>(lds + 2 * MTILE * 512);

    int tile = blockIdx.x;
    if (tile >= ntiles) return;

    // prologue: indices + stage tile0 into buf0; prefetch indices for tile+nb
    {
        int gi = 2 * (tile * 64 + w * 16) + l;
        int v0 = nidx[gi < gmax ? gi : gmax];
        stage_tile(embT, v0, lds, w, l);
    }
    int vnext;
    {
        int gi = 2 * ((tile + nb) * 64 + w * 16) + l;
        vnext = nidx[gi < gmax ? gi : gmax];
    }

    int buf = 0;
    for (; tile < ntiles; tile += nb) {
        __syncthreads();   // sync1: stage(tile) complete (vmcnt0 drain)

        const int nxt = tile + nb;
        if (nxt < ntiles)
            stage_tile(embT, vnext, lds + (buf ^ 1) * (MTILE * 512), w, l);
        // prefetch indices for tile+2*nb (consumed next iteration)
        int vfut;
        {
            int gi = 2 * ((nxt + nb) * 64 + w * 16) + l;
            vfut = nidx[gi < gmax ? gi : gmax];
        }

        // ---- GEMM1 (swapped): acc2[ht][et] = H^T[hidden][edge] ----
        const int vbuf = base0 + buf * (MTILE * 512);
        f32x4 acc2[4][4] = {};
        #pragma unroll
        for (int kki = 0; kki < 8; ++kki) {
            const int va = vbuf ^ (kki << 6);
            bf16x8 xf[4], wf[4];
            #pragma unroll
            for (int et = 0; et < 4; ++et)
                xf[et] = *reinterpret_cast<const bf16x8*>(lds + va + et * 8192);
            #pragma unroll
            for (int ht = 0; ht < 4; ++ht)
                wf[ht] = *reinterpret_cast<const bf16x8*>(
                    w1p + (size_t)(((w * 4 + ht) * 8 + kki) * 64 + l) * 8);
            #pragma unroll
            for (int ht = 0; ht < 4; ++ht)
                #pragma unroll
                for (int et = 0; et < 4; ++et)
                    acc2[ht][et] = __builtin_amdgcn_mfma_f32_16x16x32_bf16(
                        wf[ht], xf[et], acc2[ht][et], 0, 0, 0);
        }

        // ---- epilogue: relu(H+b1) then logits^T = W2^T @ . via MFMA ----
        // C/D: lane holds H^T[hidden=(lg*4+r)+ht*16+w*64][edge=et*16+lc]
        #pragma unroll
        for (int et = 0; et < 4; ++et) {
            uint32_t wd[4][2];
            #pragma unroll
            for (int ht = 0; ht < 4; ++ht) {
                float v0 = fmaxf(acc2[ht][et][0] + b1v[ht].x, 0.0f);
                float v1 = fmaxf(acc2[ht][et][1] + b1v[ht].y, 0.0f);
                float v2 = fmaxf(acc2[ht][et][2] + b1v[ht].z, 0.0f);
                float v3 = fmaxf(acc2[ht][et][3] + b1v[ht].w, 0.0f);
                asm("v_cvt_pk_bf16_f32 %0, %1, %2" : "=v"(wd[ht][0]) : "v"(v0), "v"(v1));
                asm("v_cvt_pk_bf16_f32 %0, %1, %2" : "=v"(wd[ht][1]) : "v"(v2), "v"(v3));
            }
            int4 lo4 = make_int4(wd[0][0], wd[0][1], wd[1][0], wd[1][1]);
            int4 hi4 = make_int4(wd[2][0], wd[2][1], wd[3][0], wd[3][1]);
            f32x4 a3 = {0.0f, 0.0f, 0.0f, 0.0f};
            a3 = __builtin_amdgcn_mfma_f32_16x16x32_bf16(
                af2[0], __builtin_bit_cast(bf16x8, lo4), a3, 0, 0, 0);
            a3 = __builtin_amdgcn_mfma_f32_16x16x32_bf16(
                af2[1], __builtin_bit_cast(bf16x8, hi4), a3, 0, 0, 0);
            // D3: rows 0,1 (logit cols) live in lanes lg==0, regs 0,1
            if (l < 16)
                part[w * 64 + et * 16 + l] = make_float2(a3[0], a3[1]);
        }

        // sync2: LDS-only barrier — do NOT drain vmcnt (keep prefetch in flight)
        asm volatile("s_waitcnt lgkmcnt(0)\n\ts_barrier" ::: "memory");

        if (t < 128) {
            const float* pf = reinterpret_cast<const float*>(part);
            float s = b2c + pf[t] + pf[128 + t] + pf[256 + t] + pf[384 + t];
            int m = t >> 1;
            if (tile * 64 + m < npairs)
                out[(size_t)tile * 128 + t] = s;
        }

        vnext = vfut;
        buf ^= 1;
    }
}

// ---- Fallback (validated R1): f32 gather + in-kernel convert, VALU epilogue ----
__launch_bounds__(256, 2)
__global__ void edge_mlp_f32g(const float* __restrict__ embs,
                              const int* __restrict__ nidx,
                              const u16* __restrict__ w1p,
                              const float* __restrict__ b1,
                              const float* __restrict__ W2,
                              const float* __restrict__ b2,
                              float* __restrict__ out,
                              int npairs) {
    __shared__ __align__(16) unsigned char lds[MTILE * 512 + 4 * MTILE * 2 * 4];
    const int t  = threadIdx.x;
    const int e0 = blockIdx.x * MTILE;
    {
        const int row = t >> 2;
        const int seg = t & 3;
        const int e = e0 + row;
        if (e < npairs) {
            const int i0 = nidx[2 * e];
            const int i1 = nidx[2 * e + 1];
            const float* src = (seg < 2) ? (embs + (size_t)i0 * EMB_DIM)
                                         : (embs + (size_t)i1 * EMB_DIM);
            const int cbase = (seg & 1) * 64;
            #pragma unroll
            for (int j = 0; j < 8; ++j) {
                const int c = cbase + j * 8;
                float4 f0 = *reinterpret_cast<const float4*>(src + c);
                float4 f1 = *reinterpret_cast<const float4*>(src + c + 4);
                ushort8 h;
                h[0] = f2bf(f0.x); h[1] = f2bf(f0.y);
                h[2] = f2bf(f0.z); h[3] = f2bf(f0.w);
                h[4] = f2bf(f1.x); h[5] = f2bf(f1.y);
                h[6] = f2bf(f1.z); h[7] = f2bf(f1.w);
                int off = row * 512 + (seg * 64 + j * 8) * 2;
                off ^= (row & 7) << 4;
                *reinterpret_cast<ushort8*>(lds + off) = h;
            }
        }
    }
    __syncthreads();
    const int w  = t >> 6;
    const int l  = t & 63;
    const int lg = l >> 4;
    const int lc = l & 15;
    f32x4 acc[4][4] = {};
    #pragma unroll
    for (int kki = 0; kki < 8; ++kki) {
        const int krow = kki * 32 + lg * 8;
        bf16x8 a[4], b[4];
        #pragma unroll
        for (int mt = 0; mt < 4; ++mt) {
            const int row = mt * 16 + lc;
            int off = row * 512 + krow * 2;
            off ^= (row & 7) << 4;
            a[mt] = *reinterpret_cast<const bf16x8*>(lds + off);
        }
        #pragma unroll
        for (int nt = 0; nt < 4; ++nt)
            b[nt] = *reinterpret_cast<const bf16x8*>(
                w1p + (size_t)(((w * 4 + nt) * 8 + kki) * 64 + l) * 8);
        #pragma unroll
        for (int mt = 0; mt < 4; ++mt)
            #pragma unroll
            for (int nt = 0; nt < 4; ++nt)
                acc[mt][nt] = __builtin_amdgcn_mfma_f32_16x16x32_bf16(
                    a[mt], b[nt], acc[mt][nt], 0, 0, 0);
    }
    float p0[4][4] = {}, p1[4][4] = {};
    #pragma unroll
    for (int nt = 0; nt < 4; ++nt) {
        const int n = w * 64 + nt * 16 + lc;
        const float bnv  = b1[n];
        const float w20 = W2[2 * n];
        const float w21 = W2[2 * n + 1];
        #pragma unroll
        for (int mt = 0; mt < 4; ++mt)
            #pragma unroll
            for (int r = 0; r < 4; ++r) {
                float v = fmaxf(acc[mt][nt][r] + bnv, 0.0f);
                p0[mt][r] = fmaf(v, w20, p0[mt][r]);
                p1[mt][r] = fmaf(v, w21, p1[mt][r]);
            }
    }
    #pragma unroll
    for (int mt = 0; mt < 4; ++mt)
        #pragma unroll
        for (int r = 0; r < 4; ++r) {
            float a0 = p0[mt][r], a1 = p1[mt][r];
            #pragma unroll
            for (int mask = 1; mask < 16; mask <<= 1) {
                a0 += __shfl_xor(a0, mask);
                a1 += __shfl_xor(a1, mask);
            }
            p0[mt][r] = a0; p1[mt][r] = a1;
        }
    float* part = reinterpret_cast<float*>(lds + MTILE * 512);
    if (lc == 0) {
        #pragma unroll
        for (int mt = 0; mt < 4; ++mt)
            #pragma unroll
            for (int r = 0; r < 4; ++r) {
                const int m = mt * 16 + lg * 4 + r;
                part[(w * MTILE + m) * 2 + 0] = p0[mt][r];
                part[(w * MTILE + m) * 2 + 1] = p1[mt][r];
            }
    }
    __syncthreads();
    if (t < 2 * MTILE) {
        const int m = t >> 1, c = t & 1;
        if (e0 + m < npairs) {
            float s = b2[c];
            #pragma unroll
            for (int ww = 0; ww < 4; ++ww)
                s += part[(ww * MTILE + m) * 2 + c];
            out[(size_t)(e0 + m) * 2 + c] = s;
        }
    }
}

extern "C" void kernel_launch(void* const* d_in, const int* in_sizes, int n_in,
                              void* d_out, int out_size, void* d_ws, size_t ws_size,
                              hipStream_t stream) {
    const float* embs = (const float*)d_in[0];
    const int*   nidx = (const int*)d_in[1];
    const float* W1   = (const float*)d_in[2];
    const float* b1   = (const float*)d_in[3];
    const float* W2   = (const float*)d_in[4];
    const float* b2   = (const float*)d_in[5];
    float* out = (float*)d_out;

    u16* w1p = (u16*)d_ws;                                   // 128 KiB @0
    prep_w1<<<(KDIM * HID) / 256, 256, 0, stream>>>(W1, w1p);

    const int npairs = in_sizes[1] / 2;
    const int ntiles = (npairs + MTILE - 1) / MTILE;

    const size_t w2_off   = 131072;                          // 8 KiB
    const size_t embT_off = 131072 + 8192;
    const size_t need = embT_off + (size_t)in_sizes[0] * sizeof(u16);
    if (ws_size >= need) {
        u16* w2ap = (u16*)((char*)d_ws + w2_off);
        u16* embT = (u16*)((char*)d_ws + embT_off);
        prep_w2<<<16, 256, 0, stream>>>(W2, w2ap);
        const int nemb = in_sizes[0];
        prep_embs<<<(nemb + 2047) / 2048, 256, 0, stream>>>(embs, embT, nemb);
        const int nb = NBLK < ntiles ? NBLK : ntiles;
        edge_mlp_bf2<<<nb, 256, 0, stream>>>(embT, nidx, w1p, w2ap, b1, b2,
                                             out, npairs, ntiles, nb);
    } else {
        edge_mlp_f32g<<<ntiles, 256, 0, stream>>>(embs, nidx, w1p, b1, W2, b2,
                                                  out, npairs);
    }
}

// Round 4
// 149.921 us; speedup vs baseline: 1.8456x; 1.0184x over previous
//
#include <hip/hip_runtime.h>
#include <hip/hip_bf16.h>
#include <cstdint>
#include <cstddef>

typedef unsigned short u16;
typedef __bf16 bf16x8 __attribute__((ext_vector_type(8)));
typedef u16 ushort8 __attribute__((ext_vector_type(8)));
typedef float f32x4 __attribute__((ext_vector_type(4)));

#define EMB_DIM 128
#define KDIM 256
#define HID 256
#define MTILE 64
#define NBLK 512   // 2 blocks/CU * 256 CU (LDS-limited)

static __device__ __forceinline__ u16 f2bf(float f) {
    uint32_t u = __builtin_bit_cast(uint32_t, f);
    u += 0x7fffu + ((u >> 16) & 1u);
    return (u16)(u >> 16);
}

// W1 [K=256][N=256] f32 -> MFMA fragment order, bf16 (validated R1/R2/R3).
__global__ void prep_w1(const float* __restrict__ W1, u16* __restrict__ w1p) {
    int id = blockIdx.x * blockDim.x + threadIdx.x;   // 65536
    int j   = id & 7;
    int l   = (id >> 3) & 63;
    int kki = (id >> 9) & 7;
    int ntg = id >> 12;
    int k = kki * 32 + ((l >> 4) * 8) + j;
    int n = ntg * 16 + (l & 15);
    w1p[id] = f2bf(W1[k * HID + n]);
}

// W2 [256][2] -> A-fragment with permuted k-map matching raw cvt_pk'd acc words
// (validated R3).
__global__ void prep_w2(const float* __restrict__ W2, u16* __restrict__ w2ap) {
    int id = blockIdx.x * blockDim.x + threadIdx.x;   // 4096
    if (id >= 4096) return;
    int j   = id & 7;
    int l   = (id >> 3) & 63;
    int kki = id >> 9;
    int m = l & 15;
    int g = (l >> 4) & 3;
    int k = kki * 32 + g * 4 + ((j >> 2) << 4) + (j & 3);
    w2ap[id] = (m < 2) ? f2bf(W2[k * 2 + m]) : (u16)0;
}

// Embedding table f32 -> bf16 (row-major).
__global__ void prep_embs(const float* __restrict__ in, u16* __restrict__ out, int n) {
    int id = blockIdx.x * blockDim.x + threadIdx.x;
    size_t base = (size_t)id * 8;
    if (base + 8 <= (size_t)n) {
        float4 f0 = *reinterpret_cast<const float4*>(in + base);
        float4 f1 = *reinterpret_cast<const float4*>(in + base + 4);
        ushort8 h;
        h[0] = f2bf(f0.x); h[1] = f2bf(f0.y); h[2] = f2bf(f0.z); h[3] = f2bf(f0.w);
        h[4] = f2bf(f1.x); h[5] = f2bf(f1.y); h[6] = f2bf(f1.z); h[7] = f2bf(f1.w);
        *reinterpret_cast<ushort8*>(out + base) = h;
    }
}

static __device__ __forceinline__ void gload_lds16(const void* g, void* s) {
    __builtin_amdgcn_global_load_lds(
        (const __attribute__((address_space(1))) unsigned int*)g,
        (__attribute__((address_space(3))) unsigned int*)s, 16, 0, 0);
}

// Stage 16 edge rows (wave w) of gathered bf16 X into LDS, source-swizzled
// (validated R2/R3).
static __device__ __forceinline__ void stage_tile(const u16* __restrict__ embT,
                                                  int vidx, unsigned char* xb,
                                                  int w, int l) {
    const int row_off = l >> 5;
    const int csel    = (l >> 4) & 1;
    const int c       = l & 31;
    #pragma unroll
    for (int i = 0; i < 8; ++i) {
        int n00 = __builtin_amdgcn_readlane(vidx, 4 * i + 0);
        int n01 = __builtin_amdgcn_readlane(vidx, 4 * i + 1);
        int n10 = __builtin_amdgcn_readlane(vidx, 4 * i + 2);
        int n11 = __builtin_amdgcn_readlane(vidx, 4 * i + 3);
        int na   = csel ? n01 : n00;
        int nb   = csel ? n11 : n10;
        int node = row_off ? nb : na;
        int r2   = 2 * i + row_off;
        int glow = (c ^ (r2 & 7)) & 15;
        const u16* src = embT + (size_t)node * 128 + glow * 8;
        gload_lds16(src, xb + (size_t)(w * 16 + 2 * i) * 512);
    }
}

__launch_bounds__(256, 2)
__global__ void edge_mlp_bf3(const u16* __restrict__ embT,
                             const int* __restrict__ nidx,
                             const u16* __restrict__ w1p,
                             const u16* __restrict__ w2ap,
                             const float* __restrict__ b1,
                             const float* __restrict__ b2,
                             float* __restrict__ out,
                             int npairs, int ntiles, int nb) {
    // 2 x 32 KiB X double-buffer + 2 KiB partials
    __shared__ __align__(16) unsigned char lds[2 * MTILE * 512 + 4 * MTILE * 2 * 4];
    const int t  = threadIdx.x;
    const int w  = t >> 6;
    const int l  = t & 63;
    const int lg = l >> 4;
    const int lc = l & 15;
    const int gmax = 2 * npairs - 1;

    // ---- prologue: ALL weights into registers (K-loop must be VMEM-free) ----
    // W1 fragments: 32 x bf16x8 = 128 VGPRs, loaded ONCE per persistent block.
    bf16x8 wf1[4][8];
    #pragma unroll
    for (int ht = 0; ht < 4; ++ht)
        #pragma unroll
        for (int kki = 0; kki < 8; ++kki)
            wf1[ht][kki] = *reinterpret_cast<const bf16x8*>(
                w1p + (size_t)(((w * 4 + ht) * 8 + kki) * 64 + l) * 8);
    float4 b1v[4];
    #pragma unroll
    for (int ht = 0; ht < 4; ++ht)
        b1v[ht] = *reinterpret_cast<const float4*>(b1 + w * 64 + ht * 16 + lg * 4);
    bf16x8 af2[2];
    #pragma unroll
    for (int kk = 0; kk < 2; ++kk)
        af2[kk] = *reinterpret_cast<const bf16x8*>(w2ap + (size_t)((w * 2 + kk) * 64 + l) * 8);
    const float b2c = b2[t & 1];

    // per-lane LDS read base: addr(kki,et) = (base0 ^ (kki<<6)) + et*8192 (+buf)
    const int base0 = lc * 512 + ((lg ^ (lc & 3)) << 4) + (((lc >> 2) & 1) << 6);

    float2* part = reinterpret_cast<float2*>(lds + 2 * MTILE * 512);

    int tile = blockIdx.x;

    // stage tile0 into buf0; prefetch indices for tile+nb
    {
        int gi = 2 * (tile * 64 + w * 16) + l;
        int v0 = nidx[gi < gmax ? gi : gmax];
        stage_tile(embT, v0, lds, w, l);
    }
    int vnext;
    {
        int gi = 2 * ((tile + nb) * 64 + w * 16) + l;
        vnext = nidx[gi < gmax ? gi : gmax];
    }

    int buf = 0;
    for (; tile < ntiles; tile += nb) {
        __syncthreads();   // sync1: stage(tile) complete (vmcnt0 drain)

        const int nxt = tile + nb;
        if (nxt < ntiles)
            stage_tile(embT, vnext, lds + (buf ^ 1) * (MTILE * 512), w, l);
        int vfut;
        {
            int gi = 2 * ((nxt + nb) * 64 + w * 16) + l;
            vfut = nidx[gi < gmax ? gi : gmax];
        }

        // ---- GEMM1 (swapped): acc2[ht][et] = H^T[hidden][edge] ----
        // VMEM-free: only ds_read_b128 + MFMA -> stage DMAs stay in flight.
        const int vbuf = base0 + buf * (MTILE * 512);
        f32x4 acc2[4][4] = {};
        #pragma unroll
        for (int kki = 0; kki < 8; ++kki) {
            const int va = vbuf ^ (kki << 6);
            bf16x8 xf[4];
            #pragma unroll
            for (int et = 0; et < 4; ++et)
                xf[et] = *reinterpret_cast<const bf16x8*>(lds + va + et * 8192);
            #pragma unroll
            for (int ht = 0; ht < 4; ++ht)
                #pragma unroll
                for (int et = 0; et < 4; ++et)
                    acc2[ht][et] = __builtin_amdgcn_mfma_f32_16x16x32_bf16(
                        wf1[ht][kki], xf[et], acc2[ht][et], 0, 0, 0);
        }

        // ---- epilogue: relu(H+b1) then logits^T = W2^T @ . via MFMA ----
        #pragma unroll
        for (int et = 0; et < 4; ++et) {
            uint32_t wd[4][2];
            #pragma unroll
            for (int ht = 0; ht < 4; ++ht) {
                float v0 = fmaxf(acc2[ht][et][0] + b1v[ht].x, 0.0f);
                float v1 = fmaxf(acc2[ht][et][1] + b1v[ht].y, 0.0f);
                float v2 = fmaxf(acc2[ht][et][2] + b1v[ht].z, 0.0f);
                float v3 = fmaxf(acc2[ht][et][3] + b1v[ht].w, 0.0f);
                asm("v_cvt_pk_bf16_f32 %0, %1, %2" : "=v"(wd[ht][0]) : "v"(v0), "v"(v1));
                asm("v_cvt_pk_bf16_f32 %0, %1, %2" : "=v"(wd[ht][1]) : "v"(v2), "v"(v3));
            }
            int4 lo4 = make_int4(wd[0][0], wd[0][1], wd[1][0], wd[1][1]);
            int4 hi4 = make_int4(wd[2][0], wd[2][1], wd[3][0], wd[3][1]);
            f32x4 a3 = {0.0f, 0.0f, 0.0f, 0.0f};
            a3 = __builtin_amdgcn_mfma_f32_16x16x32_bf16(
                af2[0], __builtin_bit_cast(bf16x8, lo4), a3, 0, 0, 0);
            a3 = __builtin_amdgcn_mfma_f32_16x16x32_bf16(
                af2[1], __builtin_bit_cast(bf16x8, hi4), a3, 0, 0, 0);
            if (l < 16)
                part[w * 64 + et * 16 + l] = make_float2(a3[0], a3[1]);
        }

        // sync2: LDS-only barrier — do NOT drain vmcnt (keep prefetch in flight)
        asm volatile("s_waitcnt lgkmcnt(0)\n\ts_barrier" ::: "memory");

        if (t < 128) {
            const float* pf = reinterpret_cast<const float*>(part);
            float s = b2c + pf[t] + pf[128 + t] + pf[256 + t] + pf[384 + t];
            int m = t >> 1;
            if (tile * 64 + m < npairs)
                out[(size_t)tile * 128 + t] = s;
        }

        vnext = vfut;
        buf ^= 1;
    }
}

// ---- Fallback (validated R1): f32 gather + in-kernel convert, VALU epilogue ----
__launch_bounds__(256, 2)
__global__ void edge_mlp_f32g(const float* __restrict__ embs,
                              const int* __restrict__ nidx,
                              const u16* __restrict__ w1p,
                              const float* __restrict__ b1,
                              const float* __restrict__ W2,
                              const float* __restrict__ b2,
                              float* __restrict__ out,
                              int npairs) {
    __shared__ __align__(16) unsigned char lds[MTILE * 512 + 4 * MTILE * 2 * 4];
    const int t  = threadIdx.x;
    const int e0 = blockIdx.x * MTILE;
    {
        const int row = t >> 2;
        const int seg = t & 3;
        const int e = e0 + row;
        if (e < npairs) {
            const int i0 = nidx[2 * e];
            const int i1 = nidx[2 * e + 1];
            const float* src = (seg < 2) ? (embs + (size_t)i0 * EMB_DIM)
                                         : (embs + (size_t)i1 * EMB_DIM);
            const int cbase = (seg & 1) * 64;
            #pragma unroll
            for (int j = 0; j < 8; ++j) {
                const int c = cbase + j * 8;
                float4 f0 = *reinterpret_cast<const float4*>(src + c);
                float4 f1 = *reinterpret_cast<const float4*>(src + c + 4);
                ushort8 h;
                h[0] = f2bf(f0.x); h[1] = f2bf(f0.y);
                h[2] = f2bf(f0.z); h[3] = f2bf(f0.w);
                h[4] = f2bf(f1.x); h[5] = f2bf(f1.y);
                h[6] = f2bf(f1.z); h[7] = f2bf(f1.w);
                int off = row * 512 + (seg * 64 + j * 8) * 2;
                off ^= (row & 7) << 4;
                *reinterpret_cast<ushort8*>(lds + off) = h;
            }
        }
    }
    __syncthreads();
    const int w  = t >> 6;
    const int l  = t & 63;
    const int lg = l >> 4;
    const int lc = l & 15;
    f32x4 acc[4][4] = {};
    #pragma unroll
    for (int kki = 0; kki < 8; ++kki) {
        const int krow = kki * 32 + lg * 8;
        bf16x8 a[4], b[4];
        #pragma unroll
        for (int mt = 0; mt < 4; ++mt) {
            const int row = mt * 16 + lc;
            int off = row * 512 + krow * 2;
            off ^= (row & 7) << 4;
            a[mt] = *reinterpret_cast<const bf16x8*>(lds + off);
        }
        #pragma unroll
        for (int nt = 0; nt < 4; ++nt)
            b[nt] = *reinterpret_cast<const bf16x8*>(
                w1p + (size_t)(((w * 4 + nt) * 8 + kki) * 64 + l) * 8);
        #pragma unroll
        for (int mt = 0; mt < 4; ++mt)
            #pragma unroll
            for (int nt = 0; nt < 4; ++nt)
                acc[mt][nt] = __builtin_amdgcn_mfma_f32_16x16x32_bf16(
                    a[mt], b[nt], acc[mt][nt], 0, 0, 0);
    }
    float p0[4][4] = {}, p1[4][4] = {};
    #pragma unroll
    for (int nt = 0; nt < 4; ++nt) {
        const int n = w * 64 + nt * 16 + lc;
        const float bnv  = b1[n];
        const float w20 = W2[2 * n];
        const float w21 = W2[2 * n + 1];
        #pragma unroll
        for (int mt = 0; mt < 4; ++mt)
            #pragma unroll
            for (int r = 0; r < 4; ++r) {
                float v = fmaxf(acc[mt][nt][r] + bnv, 0.0f);
                p0[mt][r] = fmaf(v, w20, p0[mt][r]);
                p1[mt][r] = fmaf(v, w21, p1[mt][r]);
            }
    }
    #pragma unroll
    for (int mt = 0; mt < 4; ++mt)
        #pragma unroll
        for (int r = 0; r < 4; ++r) {
            float a0 = p0[mt][r], a1 = p1[mt][r];
            #pragma unroll
            for (int mask = 1; mask < 16; mask <<= 1) {
                a0 += __shfl_xor(a0, mask);
                a1 += __shfl_xor(a1, mask);
            }
            p0[mt][r] = a0; p1[mt][r] = a1;
        }
    float* part = reinterpret_cast<float*>(lds + MTILE * 512);
    if (lc == 0) {
        #pragma unroll
        for (int mt = 0; mt < 4; ++mt)
            #pragma unroll
            for (int r = 0; r < 4; ++r) {
                const int m = mt * 16 + lg * 4 + r;
                part[(w * MTILE + m) * 2 + 0] = p0[mt][r];
                part[(w * MTILE + m) * 2 + 1] = p1[mt][r];
            }
    }
    __syncthreads();
    if (t < 2 * MTILE) {
        const int m = t >> 1, c = t & 1;
        if (e0 + m < npairs) {
            float s = b2[c];
            #pragma unroll
            for (int ww = 0; ww < 4; ++ww)
                s += part[(ww * MTILE + m) * 2 + c];
            out[(size_t)(e0 + m) * 2 + c] = s;
        }
    }
}

extern "C" void kernel_launch(void* const* d_in, const int* in_sizes, int n_in,
                              void* d_out, int out_size, void* d_ws, size_t ws_size,
                              hipStream_t stream) {
    const float* embs = (const float*)d_in[0];
    const int*   nidx = (const int*)d_in[1];
    const float* W1   = (const float*)d_in[2];
    const float* b1   = (const float*)d_in[3];
    const float* W2   = (const float*)d_in[4];
    const float* b2   = (const float*)d_in[5];
    float* out = (float*)d_out;

    u16* w1p = (u16*)d_ws;                                   // 128 KiB @0
    prep_w1<<<(KDIM * HID) / 256, 256, 0, stream>>>(W1, w1p);

    const int npairs = in_sizes[1] / 2;
    const int ntiles = (npairs + MTILE - 1) / MTILE;

    const size_t w2_off   = 131072;                          // 8 KiB
    const size_t embT_off = 131072 + 8192;
    const size_t need = embT_off + (size_t)in_sizes[0] * sizeof(u16);
    if (ws_size >= need) {
        u16* w2ap = (u16*)((char*)d_ws + w2_off);
        u16* embT = (u16*)((char*)d_ws + embT_off);
        prep_w2<<<16, 256, 0, stream>>>(W2, w2ap);
        const int nemb = in_sizes[0];
        prep_embs<<<(nemb + 2047) / 2048, 256, 0, stream>>>(embs, embT, nemb);
        const int nb = NBLK < ntiles ? NBLK : ntiles;
        edge_mlp_bf3<<<nb, 256, 0, stream>>>(embT, nidx, w1p, w2ap, b1, b2,
                                             out, npairs, ntiles, nb);
    } else {
        edge_mlp_f32g<<<ntiles, 256, 0, stream>>>(embs, nidx, w1p, b1, W2, b2,
                                                  out, npairs);
    }
}